// Round 14
// baseline (295.641 us; speedup 1.0000x reference)
//
#include <hip/hip_runtime.h>

// Problem constants (from reference setup_inputs)
#define DIN 200      // K (floats per x row); 50 float4s
#define DH  100      // J
#define NKT 7        // k tiles of 32 (224, padded)
#define MARGIN 2e-3f // |delta| below this -> exact fp64 fixup
#define TR   32      // rows per tile
#define NT   8       // tiles per block -> 256 rows/block -> 2048 blocks
#define RPB  (NT * TR)
#define NPASS 3      // INSTRUMENTATION (R14): surface hot-kernel counters above
                     // the ~250us harness fills. Idempotent; list appended on
                     // last pass only. hot/pass = rocprof_dur/3.

typedef _Float16 half8 __attribute__((ext_vector_type(8)));
typedef _Float16 half4 __attribute__((ext_vector_type(4)));
typedef float f32x4 __attribute__((ext_vector_type(4)));

__device__ inline half8 cvt8(float4 u, float4 v) {
  half8 h;
  h[0] = (_Float16)u.x; h[1] = (_Float16)u.y;
  h[2] = (_Float16)u.z; h[3] = (_Float16)u.w;
  h[4] = (_Float16)v.x; h[5] = (_Float16)v.y;
  h[6] = (_Float16)v.z; h[7] = (_Float16)v.w;
  return h;
}
__device__ inline half4 cvt4(float4 u) {
  half4 h;
  h[0] = (_Float16)u.x; h[1] = (_Float16)u.y;
  h[2] = (_Float16)u.z; h[3] = (_Float16)u.w;
  return h;
}

// ---------------- hot kernel: f16-MFMA GEMM sign ----------------
// x staged f32->f16 ONCE into fragment-ordered LDS (conflict-free b128 reads),
// w frags in registers (j-split across waves), single x buffer + 2 barriers.
// (256,4): natural 64 VGPR (no spill) -> 8 waves/SIMD; grid 2048 = 8 blocks/CU.
// R12 lesson: never force launch_bounds below the natural allocation (32-VGPR
// budget spilled w-frags -> 323 MB scratch).
template <bool HAVE_WS>
__global__ __launch_bounds__(256, 4)
void entmax_sign_mfma(const float* __restrict__ x,
                      const float* __restrict__ w_out,
                      const float* __restrict__ b_out,
                      const float* __restrict__ w_cat,
                      const float* __restrict__ b_cat,
                      const float* __restrict__ w2,
                      const float* __restrict__ b2,
                      float* __restrict__ out,
                      unsigned* __restrict__ cnt,
                      int* __restrict__ list) {
  // A-frags: frag f = rg*7+kt (rg=row/16, kt=k/32); lane l holds
  // x[rg*16+(l&15)][kt*32+(l>>4)*8 .. +8] as 8 f16 (16B). 14 frags x 1 KB.
  __shared__ _Float16 axf[14 * 512];      // 14336 B
  __shared__ float parts[2][4][TR];       // 1 KB, dbuf by t&1

  const int tid  = threadIdx.x;
  const int lane = tid & 63;
  const int wid  = tid >> 6;
  const int arow = lane & 15;
  const int qid  = lane >> 4;

  const float db = b_cat[0] - b_cat[1];
  const float c0 = w2[0] + b2[0];
  const float c1 = w2[1] + b2[0];

  // Zero pad slots of frags (rg,6): k in [200,224) never staged; leftover
  // LDS bits could be f16 NaN -> NaN*0 in MFMA. One-time, persists.
  for (int t2 = tid; t2 < 768; t2 += 256) {
    const int fi = t2 / 384, r2 = t2 - fi * 384;
    axf[(fi * 7 + 6) * 512 + 128 + r2] = (_Float16)0.f;
  }

  // ---- w fragments in registers: wave owns j-tiles 2*wid, 2*wid+1 ----
  half8 wf0[NKT], wf1[NKT];
  float bjv0, djv0, bjv1, djv1;
  {
    const int j0 = (2 * wid) * 16 + arow;
    const int j1 = (2 * wid + 1) * 16 + arow;   // wave 3: jt7 -> zeros
    bjv0 = (j0 < DH) ? b_out[j0] : 0.f;
    djv0 = (j0 < DH) ? (w_cat[j0] - w_cat[DH + j0]) : 0.f;
    bjv1 = (j1 < DH) ? b_out[j1] : 0.f;
    djv1 = (j1 < DH) ? (w_cat[j1] - w_cat[DH + j1]) : 0.f;
#pragma unroll
    for (int kt = 0; kt < NKT; ++kt) {
      const int k = kt * 32 + qid * 8;
      half8 h0 = {}, h1 = {};
      if (k < DIN) {
        if (j0 < DH) {
          float4 a = *(const float4*)(w_out + j0 * DIN + k);
          float4 b = *(const float4*)(w_out + j0 * DIN + k + 4);
          h0 = cvt8(a, b);
        }
        if (j1 < DH) {
          float4 a = *(const float4*)(w_out + j1 * DIN + k);
          float4 b = *(const float4*)(w_out + j1 * DIN + k + 4);
          h1 = cvt8(a, b);
        }
      }
      wf0[kt] = h0; wf1[kt] = h1;
    }
  }

  const int blockBase = blockIdx.x * RPB;
  const float4* xf4 = (const float4*)x;

  // Staging identity: thread = (row_l = tid&31, c = tid>>5); i-th load is
  // col4 = c + 8i (i=0..5; i=6 only c<2 -> wave-uniform per wave).
  const int row_l = tid & 31;
  const int cseg  = tid >> 5;
  const int wbase = (row_l >> 4) * 7 * 512 + ((row_l & 15) + (cseg >> 1) * 16) * 8
                  + (cseg & 1) * 4;

  float4 u0, u1, u2, u3, u4, u5, u6;
#define LOADT(T)                                                            \
  {                                                                         \
    const float4* xt = xf4 + (size_t)(blockBase + (T) * TR + row_l) * 50 + cseg; \
    u0 = xt[0];  u1 = xt[8];  u2 = xt[16];                                  \
    u3 = xt[24]; u4 = xt[32]; u5 = xt[40];                                  \
    if (cseg < 2) u6 = xt[48];                                              \
  }

#pragma unroll 1
  for (int pass = 0; pass < NPASS; ++pass) {
    LOADT(0);

#pragma unroll 1
    for (int t = 0; t < NT; ++t) {
      // Per-wave VMEM queue at steady state (t>=1), oldest->newest:
      // [loads(t) x7(or 6), stores(t-1) x2] -> vmcnt(2) drains exactly the
      // loads without waiting for last tile's out/dws store completion.
      // t==0 (incl. pass boundary): store/load order inverts -> vmcnt(0).
      if (t == 0) { asm volatile("s_waitcnt vmcnt(0)" ::: "memory"); }
      else        { asm volatile("s_waitcnt vmcnt(2)" ::: "memory"); }
      __builtin_amdgcn_sched_barrier(0);

      // ---- cvt + fragment-ordered LDS write ----
      *(half4*)(&axf[wbase + 0 * 512]) = cvt4(u0);
      *(half4*)(&axf[wbase + 1 * 512]) = cvt4(u1);
      *(half4*)(&axf[wbase + 2 * 512]) = cvt4(u2);
      *(half4*)(&axf[wbase + 3 * 512]) = cvt4(u3);
      *(half4*)(&axf[wbase + 4 * 512]) = cvt4(u4);
      *(half4*)(&axf[wbase + 5 * 512]) = cvt4(u5);
      if (cseg < 2) *(half4*)(&axf[wbase + 6 * 512]) = cvt4(u6);

      if (t + 1 < NT) LOADT(t + 1);                      // prefetch next tile

      asm volatile("s_waitcnt lgkmcnt(0)" ::: "memory"); // my writes done
      __builtin_amdgcn_sched_barrier(0);
      __builtin_amdgcn_s_barrier();                      // B1: tile staged

      // ---- compute: conflict-free frag reads + 28 MFMAs ----
      f32x4 acc[2][2];
#pragma unroll
      for (int rg = 0; rg < 2; ++rg)
#pragma unroll
        for (int jl = 0; jl < 2; ++jl) acc[rg][jl] = (f32x4){0.f, 0.f, 0.f, 0.f};

#pragma unroll
      for (int kt = 0; kt < NKT; ++kt)
#pragma unroll
        for (int rg = 0; rg < 2; ++rg) {
          half8 a = *(half8*)(&axf[(rg * 7 + kt) * 512 + lane * 8]);
          acc[rg][0] = __builtin_amdgcn_mfma_f32_16x16x32_f16(a, wf0[kt], acc[rg][0], 0, 0, 0);
          acc[rg][1] = __builtin_amdgcn_mfma_f32_16x16x32_f16(a, wf1[kt], acc[rg][1], 0, 0, 0);
        }

      // ---- epilogue: relu + dw-weight, 16-lane j-reduce, publish partials ----
      f32x4 part[2];
#pragma unroll
      for (int rg = 0; rg < 2; ++rg)
#pragma unroll
        for (int r = 0; r < 4; ++r)
          part[rg][r] = fmaxf(acc[rg][0][r] + bjv0, 0.f) * djv0 +
                        fmaxf(acc[rg][1][r] + bjv1, 0.f) * djv1;
#pragma unroll
      for (int m = 1; m < 16; m <<= 1)
#pragma unroll
        for (int rg = 0; rg < 2; ++rg)
#pragma unroll
          for (int r = 0; r < 4; ++r)
            part[rg][r] += __shfl_xor(part[rg][r], m, 64);

      if (arow == 0) {
        *(f32x4*)(&parts[t & 1][wid][0 * 16 + qid * 4]) = part[0];
        *(f32x4*)(&parts[t & 1][wid][1 * 16 + qid * 4]) = part[1];
      }

      asm volatile("s_waitcnt lgkmcnt(0)" ::: "memory"); // frag reads + parts done
      __builtin_amdgcn_sched_barrier(0);
      __builtin_amdgcn_s_barrier();                      // B2: buf free, parts visible

      // ---- decision: wave w owns local rows [8w, 8w+8) ----
      if (lane < 8) {
        const int rl = wid * 8 + lane;
        const float delta = parts[t & 1][0][rl] + parts[t & 1][1][rl] +
                            parts[t & 1][2][rl] + parts[t & 1][3][rl] + db;
        const int row = blockBase + t * TR + rl;
        out[row] = (delta >= 0.f) ? c0 : c1;
        if (HAVE_WS) {
          if (pass == NPASS - 1 && fabsf(delta) < MARGIN) {
            const unsigned idx = atomicAdd(cnt, 1u);   // rare (~0.5% of rows)
            list[idx] = row;
          }
        } else if (fabsf(delta) < MARGIN) {
          // Tiny-ws fallback: lane-local exact fp64 (cold, improbable path)
          const float* xr = x + (size_t)row * DIN;
          double s = (double)b_cat[0] - (double)b_cat[1];
          for (int j = 0; j < DH; ++j) {
            double a = (double)b_out[j];
            for (int k = 0; k < DIN; ++k)
              a += (double)xr[k] * (double)w_out[j * DIN + k];
            if (a > 0.0) s += a * ((double)w_cat[j] - (double)w_cat[DH + j]);
          }
          out[row] = (s >= 0.0) ? c0 : c1;
        }
      }
    }
  }
#undef LOADT
}

// ------------- cold kernel: exact fp64 sign for listed rows -------------
__global__ __launch_bounds__(256)
void entmax_fixexact(const float* __restrict__ x,
                     const float* __restrict__ w_out,
                     const float* __restrict__ b_out,
                     const float* __restrict__ w_cat,
                     const float* __restrict__ b_cat,
                     const float* __restrict__ w2,
                     const float* __restrict__ b2,
                     float* __restrict__ out,
                     const unsigned* __restrict__ cnt,
                     const int* __restrict__ list) {
  __shared__ float xs[DIN];
  __shared__ double red[128];
  const int tid = threadIdx.x;
  const unsigned count = *cnt;
  const float c0 = w2[0] + b2[0];
  const float c1 = w2[1] + b2[0];
  const double dbd = (double)b_cat[0] - (double)b_cat[1];

#pragma unroll 1
  for (unsigned i = blockIdx.x; i < count; i += gridDim.x) {
    const int row = list[i];
    if (tid < 50)
      ((float4*)xs)[tid] = ((const float4*)(x + (size_t)row * DIN))[tid];
    __syncthreads();

    double sj = 0.0;
    if (tid < DH) {
      const float4* wr = (const float4*)(w_out + tid * DIN);
      double p0 = 0.0, p1 = 0.0, p2 = 0.0, p3 = 0.0;
#pragma unroll 10
      for (int k4 = 0; k4 < 50; ++k4) {
        const float4 w4 = wr[k4];
        const float4 x4 = ((const float4*)xs)[k4];   // LDS broadcast
        p0 += (double)x4.x * (double)w4.x;
        p1 += (double)x4.y * (double)w4.y;
        p2 += (double)x4.z * (double)w4.z;
        p3 += (double)x4.w * (double)w4.w;
      }
      const double a = ((p0 + p1) + (p2 + p3)) + (double)b_out[tid];
      if (a > 0.0) sj = a * ((double)w_cat[tid] - (double)w_cat[DH + tid]);
    }
    if (tid < 128) red[tid] = (tid < DH) ? sj : 0.0;
    __syncthreads();
    if (tid < 64) {
      double v = red[tid] + red[tid + 64];
#pragma unroll
      for (int s = 1; s < 64; s <<= 1) v += __shfl_xor(v, s, 64);
      if (tid == 0) out[row] = (v + dbd >= 0.0) ? c0 : c1;
    }
    __syncthreads();   // xs/red reusable next row
  }
}

extern "C" void kernel_launch(void* const* d_in, const int* in_sizes, int n_in,
                              void* d_out, int out_size, void* d_ws, size_t ws_size,
                              hipStream_t stream) {
  const float* x     = (const float*)d_in[0];
  const float* w_out = (const float*)d_in[1];
  const float* b_out = (const float*)d_in[2];
  const float* w_cat = (const float*)d_in[3];
  const float* b_cat = (const float*)d_in[4];
  const float* w2    = (const float*)d_in[5];
  const float* b2    = (const float*)d_in[6];
  float* out = (float*)d_out;

  const int N = in_sizes[0] / DIN;     // 524288
  const int nblk = N / RPB;            // 2048 blocks x 256 rows

  if (ws_size >= 64 + (size_t)N * sizeof(int)) {
    unsigned* cnt = (unsigned*)d_ws;
    int* list = (int*)((char*)d_ws + 64);
    hipMemsetAsync(d_ws, 0, 64, stream);   // reset flagged-row counter
    entmax_sign_mfma<true><<<nblk, 256, 0, stream>>>(x, w_out, b_out, w_cat,
                                                     b_cat, w2, b2, out, cnt, list);
    entmax_fixexact<<<512, 256, 0, stream>>>(x, w_out, b_out, w_cat, b_cat,
                                             w2, b2, out, cnt, list);
  } else {
    entmax_sign_mfma<false><<<nblk, 256, 0, stream>>>(x, w_out, b_out, w_cat,
                                                      b_cat, w2, b2, out,
                                                      nullptr, nullptr);
  }
}

// Round 15
// 129.301 us; speedup vs baseline: 2.2865x; 2.2865x over previous
//
#include <hip/hip_runtime.h>

// Problem constants (from reference setup_inputs)
#define DIN 200      // K (floats per x row); 50 float4s
#define DH  100      // J
#define NKT 7        // k tiles of 32 (224, padded)
#define MARGIN 2e-3f // |delta| below this -> exact fp64 fixup
#define TR   32      // rows per tile
#define NT   8       // tiles per block -> 256 rows/block -> 2048 blocks
#define RPB  (NT * TR)
#define ABUF (14 * 512)   // f16 elems per axf buffer

typedef _Float16 half8 __attribute__((ext_vector_type(8)));
typedef _Float16 half4 __attribute__((ext_vector_type(4)));
typedef float f32x4 __attribute__((ext_vector_type(4)));

__device__ inline half8 cvt8(float4 u, float4 v) {
  half8 h;
  h[0] = (_Float16)u.x; h[1] = (_Float16)u.y;
  h[2] = (_Float16)u.z; h[3] = (_Float16)u.w;
  h[4] = (_Float16)v.x; h[5] = (_Float16)v.y;
  h[6] = (_Float16)v.z; h[7] = (_Float16)v.w;
  return h;
}
__device__ inline half4 cvt4(float4 u) {
  half4 h;
  h[0] = (_Float16)u.x; h[1] = (_Float16)u.y;
  h[2] = (_Float16)u.z; h[3] = (_Float16)u.w;
  return h;
}

// ---------------- hot kernel: f16-MFMA GEMM sign ----------------
// R15: axf DOUBLE-buffered -> staging(t+1) fully independent of compute(t);
// ONE barrier per tile (was 2); decision(t) deferred to after that barrier.
// Loads(t+1) issued a full tile period before their drain. 64-VGPR lesson
// (R12): never force launch_bounds below natural allocation.
template <bool HAVE_WS>
__global__ __launch_bounds__(256, 4)
void entmax_sign_mfma(const float* __restrict__ x,
                      const float* __restrict__ w_out,
                      const float* __restrict__ b_out,
                      const float* __restrict__ w_cat,
                      const float* __restrict__ b_cat,
                      const float* __restrict__ w2,
                      const float* __restrict__ b2,
                      float* __restrict__ out,
                      unsigned* __restrict__ cnt,
                      int* __restrict__ list) {
  // A-frags: frag f = rg*7+kt; lane l holds x[rg*16+(l&15)][kt*32+(l>>4)*8..+8]
  // as 8 f16 (16B). 14 frags x 1 KB per buffer, x2 buffers.
  __shared__ _Float16 axf[2 * ABUF];      // 28672 B
  __shared__ float parts[2][4][TR];       // 1 KB, dbuf by t&1

  const int tid  = threadIdx.x;
  const int lane = tid & 63;
  const int wid  = tid >> 6;
  const int arow = lane & 15;
  const int qid  = lane >> 4;

  const float db = b_cat[0] - b_cat[1];
  const float c0 = w2[0] + b2[0];
  const float c1 = w2[1] + b2[0];

  // Zero pad slots of frags (rg,6) in BOTH buffers: k in [200,224) never
  // staged; leftover bits could be f16 NaN -> NaN*0 in MFMA. One-time.
  for (int t2 = tid; t2 < 1536; t2 += 256) {
    const int b  = t2 / 768, r  = t2 - b * 768;
    const int fi = r / 384,  r2 = r - fi * 384;
    axf[b * ABUF + (fi * 7 + 6) * 512 + 128 + r2] = (_Float16)0.f;
  }

  // ---- w fragments in registers: wave owns j-tiles 2*wid, 2*wid+1 ----
  half8 wf0[NKT], wf1[NKT];
  float bjv0, djv0, bjv1, djv1;
  {
    const int j0 = (2 * wid) * 16 + arow;
    const int j1 = (2 * wid + 1) * 16 + arow;   // wave 3: jt7 -> zeros
    bjv0 = (j0 < DH) ? b_out[j0] : 0.f;
    djv0 = (j0 < DH) ? (w_cat[j0] - w_cat[DH + j0]) : 0.f;
    bjv1 = (j1 < DH) ? b_out[j1] : 0.f;
    djv1 = (j1 < DH) ? (w_cat[j1] - w_cat[DH + j1]) : 0.f;
#pragma unroll
    for (int kt = 0; kt < NKT; ++kt) {
      const int k = kt * 32 + qid * 8;
      half8 h0 = {}, h1 = {};
      if (k < DIN) {
        if (j0 < DH) {
          float4 a = *(const float4*)(w_out + j0 * DIN + k);
          float4 b = *(const float4*)(w_out + j0 * DIN + k + 4);
          h0 = cvt8(a, b);
        }
        if (j1 < DH) {
          float4 a = *(const float4*)(w_out + j1 * DIN + k);
          float4 b = *(const float4*)(w_out + j1 * DIN + k + 4);
          h1 = cvt8(a, b);
        }
      }
      wf0[kt] = h0; wf1[kt] = h1;
    }
  }

  const int blockBase = blockIdx.x * RPB;
  const float4* xf4 = (const float4*)x;

  // Staging identity: thread = (row_l = tid&31, c = tid>>5); i-th load is
  // col4 = c + 8i (i=0..5; i=6 only c<2 -> wave-uniform per wave).
  const int row_l = tid & 31;
  const int cseg  = tid >> 5;
  const int wbase = (row_l >> 4) * 7 * 512 + ((row_l & 15) + (cseg >> 1) * 16) * 8
                  + (cseg & 1) * 4;

  float4 u0, u1, u2, u3, u4, u5, u6;
#define LOADT(T)                                                            \
  {                                                                         \
    const float4* xt = xf4 + (size_t)(blockBase + (T) * TR + row_l) * 50 + cseg; \
    u0 = xt[0];  u1 = xt[8];  u2 = xt[16];                                  \
    u3 = xt[24]; u4 = xt[32]; u5 = xt[40];                                  \
    if (cseg < 2) u6 = xt[48];                                              \
  }
#define STAGE(BUF)                                                          \
  {                                                                         \
    _Float16* ax = axf + (BUF) * ABUF + wbase;                              \
    *(half4*)(ax + 0 * 512) = cvt4(u0);                                     \
    *(half4*)(ax + 1 * 512) = cvt4(u1);                                     \
    *(half4*)(ax + 2 * 512) = cvt4(u2);                                     \
    *(half4*)(ax + 3 * 512) = cvt4(u3);                                     \
    *(half4*)(ax + 4 * 512) = cvt4(u4);                                     \
    *(half4*)(ax + 5 * 512) = cvt4(u5);                                     \
    if (cseg < 2) *(half4*)(ax + 6 * 512) = cvt4(u6);                       \
  }

  // ---- prologue: stage tile 0 into buf 0, issue loads(1) ----
  LOADT(0);
  asm volatile("s_waitcnt vmcnt(0)" ::: "memory");
  __builtin_amdgcn_sched_barrier(0);
  STAGE(0);
  LOADT(1);
  asm volatile("s_waitcnt lgkmcnt(0)" ::: "memory");
  __builtin_amdgcn_sched_barrier(0);
  __builtin_amdgcn_s_barrier();                 // tile 0 staged (+pad zeros)

#pragma unroll 1
  for (int t = 0; t < NT; ++t) {
    // ---- compute tile t from axf[t&1]: conflict-free b128 + 28 MFMAs ----
    f32x4 acc[2][2];
#pragma unroll
    for (int rg = 0; rg < 2; ++rg)
#pragma unroll
      for (int jl = 0; jl < 2; ++jl) acc[rg][jl] = (f32x4){0.f, 0.f, 0.f, 0.f};

    const _Float16* ab = axf + (t & 1) * ABUF;
#pragma unroll
    for (int kt = 0; kt < NKT; ++kt)
#pragma unroll
      for (int rg = 0; rg < 2; ++rg) {
        half8 a = *(half8*)(ab + (rg * 7 + kt) * 512 + lane * 8);
        acc[rg][0] = __builtin_amdgcn_mfma_f32_16x16x32_f16(a, wf0[kt], acc[rg][0], 0, 0, 0);
        acc[rg][1] = __builtin_amdgcn_mfma_f32_16x16x32_f16(a, wf1[kt], acc[rg][1], 0, 0, 0);
      }

    // ---- stage tile t+1 into axf[(t+1)&1] (independent of compute) ----
    if (t + 1 < NT) {
      // VMEM queue oldest->newest: [loads(t+1) x7(6), stores(t-1) x2(3)]
      // -> vmcnt(2 or 3) drains exactly the loads. t==0: no stores yet -> 0.
      if (t == 0)      { asm volatile("s_waitcnt vmcnt(0)" ::: "memory"); }
      else if (HAVE_WS){ asm volatile("s_waitcnt vmcnt(3)" ::: "memory"); }
      else             { asm volatile("s_waitcnt vmcnt(2)" ::: "memory"); }
      __builtin_amdgcn_sched_barrier(0);
      STAGE((t + 1) & 1);
      if (t + 2 < NT) LOADT(t + 2);
    }

    // ---- epilogue: relu + dw-weight, 16-lane j-reduce, publish partials ----
    f32x4 part[2];
#pragma unroll
    for (int rg = 0; rg < 2; ++rg)
#pragma unroll
      for (int r = 0; r < 4; ++r)
        part[rg][r] = fmaxf(acc[rg][0][r] + bjv0, 0.f) * djv0 +
                      fmaxf(acc[rg][1][r] + bjv1, 0.f) * djv1;
#pragma unroll
    for (int m = 1; m < 16; m <<= 1)
#pragma unroll
      for (int rg = 0; rg < 2; ++rg)
#pragma unroll
        for (int r = 0; r < 4; ++r)
          part[rg][r] += __shfl_xor(part[rg][r], m, 64);

    if (arow == 0) {
      *(f32x4*)(&parts[t & 1][wid][0 * 16 + qid * 4]) = part[0];
      *(f32x4*)(&parts[t & 1][wid][1 * 16 + qid * 4]) = part[1];
    }

    asm volatile("s_waitcnt lgkmcnt(0)" ::: "memory"); // reads(t)+writes done
    __builtin_amdgcn_sched_barrier(0);
    __builtin_amdgcn_s_barrier();   // ONE barrier: buf(t) free, buf(t+1) &
                                    // parts(t) visible

    // ---- decision tile t (post-barrier; wave w owns local rows [8w,8w+8)) ----
    if (lane < 8) {
      const int rl = wid * 8 + lane;
      const float delta = parts[t & 1][0][rl] + parts[t & 1][1][rl] +
                          parts[t & 1][2][rl] + parts[t & 1][3][rl] + db;
      const int row = blockBase + t * TR + rl;
      out[row] = (delta >= 0.f) ? c0 : c1;
      if (HAVE_WS) {
        dws_store:
        if (fabsf(delta) < MARGIN) {
          const unsigned idx = atomicAdd(cnt, 1u);   // rare (~0.5% of rows)
          list[idx] = row;
        }
      } else if (fabsf(delta) < MARGIN) {
        // Tiny-ws fallback: lane-local exact fp64 (cold, improbable path)
        const float* xr = x + (size_t)row * DIN;
        double s = (double)b_cat[0] - (double)b_cat[1];
        for (int j = 0; j < DH; ++j) {
          double a = (double)b_out[j];
          for (int k = 0; k < DIN; ++k)
            a += (double)xr[k] * (double)w_out[j * DIN + k];
          if (a > 0.0) s += a * ((double)w_cat[j] - (double)w_cat[DH + j]);
        }
        out[row] = (s >= 0.0) ? c0 : c1;
      }
    }
  }
#undef LOADT
#undef STAGE
}

// ------------- cold kernel: exact fp64 sign for listed rows -------------
__global__ __launch_bounds__(256)
void entmax_fixexact(const float* __restrict__ x,
                     const float* __restrict__ w_out,
                     const float* __restrict__ b_out,
                     const float* __restrict__ w_cat,
                     const float* __restrict__ b_cat,
                     const float* __restrict__ w2,
                     const float* __restrict__ b2,
                     float* __restrict__ out,
                     const unsigned* __restrict__ cnt,
                     const int* __restrict__ list) {
  __shared__ float xs[DIN];
  __shared__ double red[128];
  const int tid = threadIdx.x;
  const unsigned count = *cnt;
  const float c0 = w2[0] + b2[0];
  const float c1 = w2[1] + b2[0];
  const double dbd = (double)b_cat[0] - (double)b_cat[1];

#pragma unroll 1
  for (unsigned i = blockIdx.x; i < count; i += gridDim.x) {
    const int row = list[i];
    if (tid < 50)
      ((float4*)xs)[tid] = ((const float4*)(x + (size_t)row * DIN))[tid];
    __syncthreads();

    double sj = 0.0;
    if (tid < DH) {
      const float4* wr = (const float4*)(w_out + tid * DIN);
      double p0 = 0.0, p1 = 0.0, p2 = 0.0, p3 = 0.0;
#pragma unroll 10
      for (int k4 = 0; k4 < 50; ++k4) {
        const float4 w4 = wr[k4];
        const float4 x4 = ((const float4*)xs)[k4];   // LDS broadcast
        p0 += (double)x4.x * (double)w4.x;
        p1 += (double)x4.y * (double)w4.y;
        p2 += (double)x4.z * (double)w4.z;
        p3 += (double)x4.w * (double)w4.w;
      }
      const double a = ((p0 + p1) + (p2 + p3)) + (double)b_out[tid];
      if (a > 0.0) sj = a * ((double)w_cat[tid] - (double)w_cat[DH + tid]);
    }
    if (tid < 128) red[tid] = (tid < DH) ? sj : 0.0;
    __syncthreads();
    if (tid < 64) {
      double v = red[tid] + red[tid + 64];
#pragma unroll
      for (int s = 1; s < 64; s <<= 1) v += __shfl_xor(v, s, 64);
      if (tid == 0) out[row] = (v + dbd >= 0.0) ? c0 : c1;
    }
    __syncthreads();   // xs/red reusable next row
  }
}

extern "C" void kernel_launch(void* const* d_in, const int* in_sizes, int n_in,
                              void* d_out, int out_size, void* d_ws, size_t ws_size,
                              hipStream_t stream) {
  const float* x     = (const float*)d_in[0];
  const float* w_out = (const float*)d_in[1];
  const float* b_out = (const float*)d_in[2];
  const float* w_cat = (const float*)d_in[3];
  const float* b_cat = (const float*)d_in[4];
  const float* w2    = (const float*)d_in[5];
  const float* b2    = (const float*)d_in[6];
  float* out = (float*)d_out;

  const int N = in_sizes[0] / DIN;     // 524288
  const int nblk = N / RPB;            // 2048 blocks x 256 rows

  if (ws_size >= 64 + (size_t)N * sizeof(int)) {
    unsigned* cnt = (unsigned*)d_ws;
    int* list = (int*)((char*)d_ws + 64);
    hipMemsetAsync(d_ws, 0, 64, stream);   // reset flagged-row counter
    entmax_sign_mfma<true><<<nblk, 256, 0, stream>>>(x, w_out, b_out, w_cat,
                                                     b_cat, w2, b2, out, cnt, list);
    entmax_fixexact<<<512, 256, 0, stream>>>(x, w_out, b_out, w_cat, b_cat,
                                             w2, b2, out, cnt, list);
  } else {
    entmax_sign_mfma<false><<<nblk, 256, 0, stream>>>(x, w_out, b_out, w_cat,
                                                      b_cat, w2, b2, out,
                                                      nullptr, nullptr);
  }
}

// Round 16
// 126.352 us; speedup vs baseline: 2.3398x; 1.0233x over previous
//
#include <hip/hip_runtime.h>

// Problem constants (from reference setup_inputs)
#define DIN 200      // K (floats per x row); 50 float4s
#define DH  100      // J
#define NKT 7        // k tiles of 32 (224, padded)
#define MARGIN 2e-3f // |delta| below this -> exact fp64 fixup
#define TR   32      // rows per tile
#define NT   8       // tiles per block -> 256 rows/block -> 2048 blocks
#define RPB  (NT * TR)
#define ABUF (14 * 512)   // f16 elems per axf buffer

typedef _Float16 half8 __attribute__((ext_vector_type(8)));
typedef _Float16 half4 __attribute__((ext_vector_type(4)));
typedef float f32x4 __attribute__((ext_vector_type(4)));

__device__ inline half8 cvt8(float4 u, float4 v) {
  half8 h;
  h[0] = (_Float16)u.x; h[1] = (_Float16)u.y;
  h[2] = (_Float16)u.z; h[3] = (_Float16)u.w;
  h[4] = (_Float16)v.x; h[5] = (_Float16)v.y;
  h[6] = (_Float16)v.z; h[7] = (_Float16)v.w;
  return h;
}
__device__ inline half4 cvt4(float4 u) {
  half4 h;
  h[0] = (_Float16)u.x; h[1] = (_Float16)u.y;
  h[2] = (_Float16)u.z; h[3] = (_Float16)u.w;
  return h;
}

// ---------------- hot kernel: f16-MFMA GEMM sign ----------------
// R16: launch_bounds (256,2) -> VGPR cap 256. The live set is ~110 regs
// (wf 56 + staging 28 + acc 16 + misc); under (256,4) the compiler pinned
// 64 VGPR and spilled ~12-20 MB/pass to scratch (R11/R14 WRITE_SIZE),
// injecting scratch VMEM into every tile's wait chain. Trade nominal
// occupancy (16 waves/CU, same as measured before) for a spill-free loop.
// R12 lesson generalized: the register budget must cover the live set.
template <bool HAVE_WS>
__global__ __launch_bounds__(256, 2)
void entmax_sign_mfma(const float* __restrict__ x,
                      const float* __restrict__ w_out,
                      const float* __restrict__ b_out,
                      const float* __restrict__ w_cat,
                      const float* __restrict__ b_cat,
                      const float* __restrict__ w2,
                      const float* __restrict__ b2,
                      float* __restrict__ out,
                      unsigned* __restrict__ cnt,
                      int* __restrict__ list) {
  // A-frags: frag f = rg*7+kt; lane l holds x[rg*16+(l&15)][kt*32+(l>>4)*8..+8]
  // as 8 f16 (16B). 14 frags x 1 KB per buffer, x2 buffers.
  __shared__ _Float16 axf[2 * ABUF];      // 28672 B
  __shared__ float parts[2][4][TR];       // 1 KB, dbuf by t&1

  const int tid  = threadIdx.x;
  const int lane = tid & 63;
  const int wid  = tid >> 6;
  const int arow = lane & 15;
  const int qid  = lane >> 4;

  const float db = b_cat[0] - b_cat[1];
  const float c0 = w2[0] + b2[0];
  const float c1 = w2[1] + b2[0];

  // Zero pad slots of frags (rg,6) in BOTH buffers: k in [200,224) never
  // staged; leftover bits could be f16 NaN -> NaN*0 in MFMA. One-time.
  for (int t2 = tid; t2 < 1536; t2 += 256) {
    const int b  = t2 / 768, r  = t2 - b * 768;
    const int fi = r / 384,  r2 = r - fi * 384;
    axf[b * ABUF + (fi * 7 + 6) * 512 + 128 + r2] = (_Float16)0.f;
  }

  // ---- w fragments in registers: wave owns j-tiles 2*wid, 2*wid+1 ----
  half8 wf0[NKT], wf1[NKT];
  float bjv0, djv0, bjv1, djv1;
  {
    const int j0 = (2 * wid) * 16 + arow;
    const int j1 = (2 * wid + 1) * 16 + arow;   // wave 3: jt7 -> zeros
    bjv0 = (j0 < DH) ? b_out[j0] : 0.f;
    djv0 = (j0 < DH) ? (w_cat[j0] - w_cat[DH + j0]) : 0.f;
    bjv1 = (j1 < DH) ? b_out[j1] : 0.f;
    djv1 = (j1 < DH) ? (w_cat[j1] - w_cat[DH + j1]) : 0.f;
#pragma unroll
    for (int kt = 0; kt < NKT; ++kt) {
      const int k = kt * 32 + qid * 8;
      half8 h0 = {}, h1 = {};
      if (k < DIN) {
        if (j0 < DH) {
          float4 a = *(const float4*)(w_out + j0 * DIN + k);
          float4 b = *(const float4*)(w_out + j0 * DIN + k + 4);
          h0 = cvt8(a, b);
        }
        if (j1 < DH) {
          float4 a = *(const float4*)(w_out + j1 * DIN + k);
          float4 b = *(const float4*)(w_out + j1 * DIN + k + 4);
          h1 = cvt8(a, b);
        }
      }
      wf0[kt] = h0; wf1[kt] = h1;
    }
  }

  const int blockBase = blockIdx.x * RPB;
  const float4* xf4 = (const float4*)x;

  // Staging identity: thread = (row_l = tid&31, c = tid>>5); i-th load is
  // col4 = c + 8i (i=0..5; i=6 only c<2 -> wave-uniform per wave).
  const int row_l = tid & 31;
  const int cseg  = tid >> 5;
  const int wbase = (row_l >> 4) * 7 * 512 + ((row_l & 15) + (cseg >> 1) * 16) * 8
                  + (cseg & 1) * 4;

  float4 u0, u1, u2, u3, u4, u5, u6;
#define LOADT(T)                                                            \
  {                                                                         \
    const float4* xt = xf4 + (size_t)(blockBase + (T) * TR + row_l) * 50 + cseg; \
    u0 = xt[0];  u1 = xt[8];  u2 = xt[16];                                  \
    u3 = xt[24]; u4 = xt[32]; u5 = xt[40];                                  \
    if (cseg < 2) u6 = xt[48];                                              \
  }
#define STAGE(BUF)                                                          \
  {                                                                         \
    _Float16* ax = axf + (BUF) * ABUF + wbase;                              \
    *(half4*)(ax + 0 * 512) = cvt4(u0);                                     \
    *(half4*)(ax + 1 * 512) = cvt4(u1);                                     \
    *(half4*)(ax + 2 * 512) = cvt4(u2);                                     \
    *(half4*)(ax + 3 * 512) = cvt4(u3);                                     \
    *(half4*)(ax + 4 * 512) = cvt4(u4);                                     \
    *(half4*)(ax + 5 * 512) = cvt4(u5);                                     \
    if (cseg < 2) *(half4*)(ax + 6 * 512) = cvt4(u6);                       \
  }

  // ---- prologue: stage tile 0 into buf 0, issue loads(1) ----
  LOADT(0);
  asm volatile("s_waitcnt vmcnt(0)" ::: "memory");
  __builtin_amdgcn_sched_barrier(0);
  STAGE(0);
  LOADT(1);
  asm volatile("s_waitcnt lgkmcnt(0)" ::: "memory");
  __builtin_amdgcn_sched_barrier(0);
  __builtin_amdgcn_s_barrier();                 // tile 0 staged (+pad zeros)

#pragma unroll 1
  for (int t = 0; t < NT; ++t) {
    // ---- compute tile t from axf[t&1]: conflict-free b128 + 28 MFMAs ----
    f32x4 acc[2][2];
#pragma unroll
    for (int rg = 0; rg < 2; ++rg)
#pragma unroll
      for (int jl = 0; jl < 2; ++jl) acc[rg][jl] = (f32x4){0.f, 0.f, 0.f, 0.f};

    const _Float16* ab = axf + (t & 1) * ABUF;
#pragma unroll
    for (int kt = 0; kt < NKT; ++kt)
#pragma unroll
      for (int rg = 0; rg < 2; ++rg) {
        half8 a = *(half8*)(ab + (rg * 7 + kt) * 512 + lane * 8);
        acc[rg][0] = __builtin_amdgcn_mfma_f32_16x16x32_f16(a, wf0[kt], acc[rg][0], 0, 0, 0);
        acc[rg][1] = __builtin_amdgcn_mfma_f32_16x16x32_f16(a, wf1[kt], acc[rg][1], 0, 0, 0);
      }

    // ---- stage tile t+1 into axf[(t+1)&1] (independent of compute) ----
    if (t + 1 < NT) {
      // VMEM queue oldest->newest: [loads(t+1) x7(6), out-store(t-1) x1]
      // -> vmcnt(1) drains exactly the loads. t==0: no store yet -> 0.
      // (Spill-free now, so this queue accounting is real.)
      if (t == 0) { asm volatile("s_waitcnt vmcnt(0)" ::: "memory"); }
      else        { asm volatile("s_waitcnt vmcnt(1)" ::: "memory"); }
      __builtin_amdgcn_sched_barrier(0);
      STAGE((t + 1) & 1);
      if (t + 2 < NT) LOADT(t + 2);
    }

    // ---- epilogue: relu + dw-weight, 16-lane j-reduce, publish partials ----
    f32x4 part[2];
#pragma unroll
    for (int rg = 0; rg < 2; ++rg)
#pragma unroll
      for (int r = 0; r < 4; ++r)
        part[rg][r] = fmaxf(acc[rg][0][r] + bjv0, 0.f) * djv0 +
                      fmaxf(acc[rg][1][r] + bjv1, 0.f) * djv1;
#pragma unroll
    for (int m = 1; m < 16; m <<= 1)
#pragma unroll
      for (int rg = 0; rg < 2; ++rg)
#pragma unroll
        for (int r = 0; r < 4; ++r)
          part[rg][r] += __shfl_xor(part[rg][r], m, 64);

    if (arow == 0) {
      *(f32x4*)(&parts[t & 1][wid][0 * 16 + qid * 4]) = part[0];
      *(f32x4*)(&parts[t & 1][wid][1 * 16 + qid * 4]) = part[1];
    }

    asm volatile("s_waitcnt lgkmcnt(0)" ::: "memory"); // reads(t)+writes done
    __builtin_amdgcn_sched_barrier(0);
    __builtin_amdgcn_s_barrier();   // ONE barrier: buf(t) free, buf(t+1) &
                                    // parts(t) visible

    // ---- decision tile t (post-barrier; wave w owns local rows [8w,8w+8)) ----
    if (lane < 8) {
      const int rl = wid * 8 + lane;
      const float delta = parts[t & 1][0][rl] + parts[t & 1][1][rl] +
                          parts[t & 1][2][rl] + parts[t & 1][3][rl] + db;
      const int row = blockBase + t * TR + rl;
      out[row] = (delta >= 0.f) ? c0 : c1;
      if (HAVE_WS) {
        if (fabsf(delta) < MARGIN) {
          const unsigned idx = atomicAdd(cnt, 1u);   // rare (~0.5% of rows)
          list[idx] = row;
        }
      } else if (fabsf(delta) < MARGIN) {
        // Tiny-ws fallback: lane-local exact fp64 (cold, improbable path)
        const float* xr = x + (size_t)row * DIN;
        double s = (double)b_cat[0] - (double)b_cat[1];
        for (int j = 0; j < DH; ++j) {
          double a = (double)b_out[j];
          for (int k = 0; k < DIN; ++k)
            a += (double)xr[k] * (double)w_out[j * DIN + k];
          if (a > 0.0) s += a * ((double)w_cat[j] - (double)w_cat[DH + j]);
        }
        out[row] = (s >= 0.0) ? c0 : c1;
      }
    }
  }
#undef LOADT
#undef STAGE
}

// ------------- cold kernel: exact fp64 sign for listed rows -------------
__global__ __launch_bounds__(256)
void entmax_fixexact(const float* __restrict__ x,
                     const float* __restrict__ w_out,
                     const float* __restrict__ b_out,
                     const float* __restrict__ w_cat,
                     const float* __restrict__ b_cat,
                     const float* __restrict__ w2,
                     const float* __restrict__ b2,
                     float* __restrict__ out,
                     const unsigned* __restrict__ cnt,
                     const int* __restrict__ list) {
  __shared__ float xs[DIN];
  __shared__ double red[128];
  const int tid = threadIdx.x;
  const unsigned count = *cnt;
  const float c0 = w2[0] + b2[0];
  const float c1 = w2[1] + b2[0];
  const double dbd = (double)b_cat[0] - (double)b_cat[1];

#pragma unroll 1
  for (unsigned i = blockIdx.x; i < count; i += gridDim.x) {
    const int row = list[i];
    if (tid < 50)
      ((float4*)xs)[tid] = ((const float4*)(x + (size_t)row * DIN))[tid];
    __syncthreads();

    double sj = 0.0;
    if (tid < DH) {
      const float4* wr = (const float4*)(w_out + tid * DIN);
      double p0 = 0.0, p1 = 0.0, p2 = 0.0, p3 = 0.0;
#pragma unroll 10
      for (int k4 = 0; k4 < 50; ++k4) {
        const float4 w4 = wr[k4];
        const float4 x4 = ((const float4*)xs)[k4];   // LDS broadcast
        p0 += (double)x4.x * (double)w4.x;
        p1 += (double)x4.y * (double)w4.y;
        p2 += (double)x4.z * (double)w4.z;
        p3 += (double)x4.w * (double)w4.w;
      }
      const double a = ((p0 + p1) + (p2 + p3)) + (double)b_out[tid];
      if (a > 0.0) sj = a * ((double)w_cat[tid] - (double)w_cat[DH + tid]);
    }
    if (tid < 128) red[tid] = (tid < DH) ? sj : 0.0;
    __syncthreads();
    if (tid < 64) {
      double v = red[tid] + red[tid + 64];
#pragma unroll
      for (int s = 1; s < 64; s <<= 1) v += __shfl_xor(v, s, 64);
      if (tid == 0) out[row] = (v + dbd >= 0.0) ? c0 : c1;
    }
    __syncthreads();   // xs/red reusable next row
  }
}

extern "C" void kernel_launch(void* const* d_in, const int* in_sizes, int n_in,
                              void* d_out, int out_size, void* d_ws, size_t ws_size,
                              hipStream_t stream) {
  const float* x     = (const float*)d_in[0];
  const float* w_out = (const float*)d_in[1];
  const float* b_out = (const float*)d_in[2];
  const float* w_cat = (const float*)d_in[3];
  const float* b_cat = (const float*)d_in[4];
  const float* w2    = (const float*)d_in[5];
  const float* b2    = (const float*)d_in[6];
  float* out = (float*)d_out;

  const int N = in_sizes[0] / DIN;     // 524288
  const int nblk = N / RPB;            // 2048 blocks x 256 rows

  if (ws_size >= 64 + (size_t)N * sizeof(int)) {
    unsigned* cnt = (unsigned*)d_ws;
    int* list = (int*)((char*)d_ws + 64);
    hipMemsetAsync(d_ws, 0, 64, stream);   // reset flagged-row counter
    entmax_sign_mfma<true><<<nblk, 256, 0, stream>>>(x, w_out, b_out, w_cat,
                                                     b_cat, w2, b2, out, cnt, list);
    entmax_fixexact<<<512, 256, 0, stream>>>(x, w_out, b_out, w_cat, b_cat,
                                             w2, b2, out, cnt, list);
  } else {
    entmax_sign_mfma<false><<<nblk, 256, 0, stream>>>(x, w_out, b_out, w_cat,
                                                      b_cat, w2, b2, out,
                                                      nullptr, nullptr);
  }
}